// Round 14
// baseline (168.883 us; speedup 1.0000x reference)
//
#include <hip/hip_runtime.h>

typedef __attribute__((ext_vector_type(8))) short bf16x8;
typedef __attribute__((ext_vector_type(16))) float f32x16;

#define MFMA32 __builtin_amdgcn_mfma_f32_32x32x16_bf16

__device__ __forceinline__ unsigned short bf16r(float f){
  unsigned u = __builtin_bit_cast(unsigned, f);
  unsigned r = (u + 0x7FFFu + ((u >> 16) & 1u)) >> 16;
  return (unsigned short)r;
}
__device__ __forceinline__ unsigned bfpack2(float a, float b){
  unsigned ua = __builtin_bit_cast(unsigned, a);
  unsigned ub = __builtin_bit_cast(unsigned, b);
  unsigned ra = (ua + 0x7FFFu + ((ua >> 16) & 1u)) >> 16;
  unsigned rb = (ub + 0x7FFFu + ((ub >> 16) & 1u)) & 0xFFFF0000u;
  return (ra & 0xFFFFu) | rb;
}
__device__ __forceinline__ float bf2f(unsigned short h){
  unsigned u = ((unsigned)h) << 16;
  return __builtin_bit_cast(float, u);
}
__device__ __forceinline__ float ubits(unsigned u){
  return __builtin_bit_cast(float, u);
}
__device__ __forceinline__ unsigned cvtpk_bf16(float a, float b){
  unsigned r;
  asm("v_cvt_pk_bf16_f32 %0, %1, %2" : "=v"(r) : "v"(a), "v"(b));
  return r;
}
__device__ __forceinline__ void permswap(unsigned &x, unsigned &y){
  asm volatile("v_permlane32_swap_b32 %0, %1" : "+v"(x), "+v"(y));
}
__device__ __forceinline__ float fexp2(float x){     // raw v_exp_f32 (2^x)
  float r; asm("v_exp_f32 %0, %1" : "=v"(r) : "v"(x)); return r;
}

// ---------------- weight transpose: W[k][n] f32 -> WT[n][k] bf16 (512x512, 4 mats)
__global__ __launch_bounds__(256) void wt_kernel(
    const float* __restrict__ W0, const float* __restrict__ W1,
    const float* __restrict__ W2, const float* __restrict__ W3,
    unsigned short* __restrict__ T0, unsigned short* __restrict__ T1,
    unsigned short* __restrict__ T2, unsigned short* __restrict__ T3)
{
  int z = blockIdx.z;
  const float* W = z==0?W0 : z==1?W1 : z==2?W2 : W3;
  unsigned short* T = z==0?T0 : z==1?T1 : z==2?T2 : T3;
  __shared__ float tile[64][68];
  int kb0 = blockIdx.x*64, nb0 = blockIdx.y*64;
  int tid = threadIdx.x;
#pragma unroll
  for (int i=0;i<4;++i){
    int c = tid + i*256; int r = c>>4, cc = (c&15)*4;
    *(float4*)&tile[r][cc] = *(const float4*)&W[(kb0+r)*512 + nb0 + cc];
  }
  __syncthreads();
#pragma unroll
  for (int i=0;i<4;++i){
    int c = tid + i*256; int o = c*4; int n = o>>6, kk = o&63;
    ushort4 pk;
    pk.x = bf16r(tile[kk+0][n]); pk.y = bf16r(tile[kk+1][n]);
    pk.z = bf16r(tile[kk+2][n]); pk.w = bf16r(tile[kk+3][n]);
    *(ushort4*)&T[(nb0+n)*512 + kb0 + kk] = pk;
  }
}

// ---------------- fused QKV projection. grid (64,4,3).
// z=0: q = Q@Wq+bq           -> qbuf (bf16)
// z=1: k = (K@Wk+bk)*scale_m -> kbuf (bf16), scale_m = log2e/(sqrt(512)*temp[m])
// z=2: v = K@Wv+bv           -> vt (bf16, tile-major [b][kt32][d][kk32]) via LDS transpose
__global__ __launch_bounds__(256,2) void qkv_kernel(
    const float* __restrict__ Qin, const float* __restrict__ Kin,
    const unsigned short* __restrict__ WqT, const unsigned short* __restrict__ WkT,
    const unsigned short* __restrict__ WvT,
    const float* __restrict__ bq, const float* __restrict__ bk,
    const float* __restrict__ bv, const float* __restrict__ temp,
    unsigned short* __restrict__ qbuf, unsigned short* __restrict__ kbuf,
    unsigned short* __restrict__ vt)
{
  const float RS2K = 0.044194173824159216f * 1.4426950408889634f;
  __shared__ short SM[128*144];                    // As|Bs, reused as Lt[128][144]
  short (*As)[72] = (short(*)[72])SM;
  short (*Bs)[72] = (short(*)[72])(SM + 128*72);
  int z = blockIdx.z;
  const float* A = (z==0) ? Qin : Kin;
  const unsigned short* BT = z==0 ? WqT : (z==1 ? WkT : WvT);
  const float* bias = z==0 ? bq : (z==1 ? bk : bv);
  int m0 = blockIdx.x*128, n0 = blockIdx.y*128;
  int tid = threadIdx.x;
  int lane = tid & 63, w = tid >> 6, l5 = lane & 31, hi = lane >> 5;
  int wr = w >> 1, wc = w & 1;
  f32x16 acc00, acc01, acc10, acc11;
#pragma unroll
  for (int i=0;i<16;++i){ acc00[i]=0.f; acc01[i]=0.f; acc10[i]=0.f; acc11[i]=0.f; }

  for (int kt=0; kt<8; ++kt){
    int k0 = kt*64;
    __syncthreads();
#pragma unroll
    for (int i=0;i<4;++i){
      int c = tid + i*256; int r = c>>3, cc = (c&7)*8;
      const float* src = &A[(m0+r)*512 + k0 + cc];
      float4 v0 = *(const float4*)src;
      float4 v1 = *(const float4*)(src+4);
      uint4 pk;
      pk.x = bfpack2(v0.x, v0.y); pk.y = bfpack2(v0.z, v0.w);
      pk.z = bfpack2(v1.x, v1.y); pk.w = bfpack2(v1.z, v1.w);
      *(uint4*)&As[r][cc] = pk;
    }
#pragma unroll
    for (int i=0;i<4;++i){
      int c = tid + i*256; int r = c>>3, cc = (c&7)*8;
      *(uint4*)&Bs[r][cc] = *(const uint4*)&BT[(n0+r)*512 + k0 + cc];
    }
    __syncthreads();
#pragma unroll
    for (int ks=0; ks<4; ++ks){
      bf16x8 a0 = *(const bf16x8*)&As[wr*64 + l5     ][ks*16 + hi*8];
      bf16x8 a1 = *(const bf16x8*)&As[wr*64 + 32 + l5][ks*16 + hi*8];
      bf16x8 b0 = *(const bf16x8*)&Bs[wc*64 + l5     ][ks*16 + hi*8];
      bf16x8 b1 = *(const bf16x8*)&Bs[wc*64 + 32 + l5][ks*16 + hi*8];
      acc00 = MFMA32(a0, b0, acc00, 0,0,0);
      acc01 = MFMA32(a0, b1, acc01, 0,0,0);
      acc10 = MFMA32(a1, b0, acc10, 0,0,0);
      acc11 = MFMA32(a1, b1, acc11, 0,0,0);
    }
  }

  if (z <= 1){
    unsigned short* Cout = (z==0) ? qbuf : kbuf;
#pragma unroll
    for (int mt=0; mt<2; ++mt){
      float sc[16];
      if (z==1){
        int mb = m0 + wr*64 + mt*32 + 4*hi;
#pragma unroll
        for (int qd=0; qd<4; ++qd)
#pragma unroll
        for (int j=0; j<4; ++j)
          sc[qd*4+j] = RS2K*__builtin_amdgcn_rcpf(temp[mb + qd*8 + j]);
      }
#pragma unroll
      for (int nt=0; nt<2; ++nt){
        const f32x16& acc = mt==0 ? (nt==0?acc00:acc01) : (nt==0?acc10:acc11);
        int n = n0 + wc*64 + nt*32 + l5;
        float bn = bias[n];
#pragma unroll
        for (int r=0;r<16;++r){
          int m = m0 + wr*64 + mt*32 + (r&3) + 8*(r>>2) + 4*hi;
          float v = acc[r] + bn;
          if (z==1) v *= sc[r];
          Cout[m*512 + n] = bf16r(v);
        }
      }
    }
  } else {
    // ---- V: transpose via LDS, store tile-major
    __syncthreads();                       // done reading As/Bs
    short* Lt = SM;                        // [128 n][144 m-stride]
#pragma unroll
    for (int mt=0; mt<2; ++mt)
#pragma unroll
    for (int nt=0; nt<2; ++nt){
      const f32x16& acc = mt==0 ? (nt==0?acc00:acc01) : (nt==0?acc10:acc11);
      int n = wc*64 + nt*32 + l5;
      float bn = bias[n0 + n];
#pragma unroll
      for (int qd=0; qd<4; ++qd){
        int mloc = wr*64 + mt*32 + qd*8 + 4*hi;
        uint2 pk;
        pk.x = bfpack2(acc[qd*4+0]+bn, acc[qd*4+1]+bn);
        pk.y = bfpack2(acc[qd*4+2]+bn, acc[qd*4+3]+bn);
        *(uint2*)&Lt[n*144 + mloc] = pk;
      }
    }
    __syncthreads();
    int b = m0 >> 11;
    int ktb = (m0 & 2047) >> 5;
#pragma unroll
    for (int pass=0; pass<2; ++pass){
      int d = (tid>>2) + pass*64;
      int kk0 = (tid&3)*8;
#pragma unroll
      for (int kt=0; kt<4; ++kt){
        uint4 v = *(const uint4*)&Lt[d*144 + kt*32 + kk0];
        *(uint4*)&vt[(size_t)((b*64 + ktb + kt)*512 + n0 + d)*32 + kk0] = v;
      }
    }
  }
}

// ---------------- GEMM (O-projection): C = relu(A@W + bias) + resid -> bf16
__global__ __launch_bounds__(256,2) void gemm_o_kernel(
    const unsigned short* __restrict__ A, const unsigned short* __restrict__ BT,
    const float* __restrict__ bias, unsigned short* __restrict__ Cout,
    const unsigned short* __restrict__ resid)
{
  __shared__ short As[128][72];
  __shared__ short Bs[128][72];
  int m0 = blockIdx.x*128, n0 = blockIdx.y*128;
  int tid = threadIdx.x;
  int lane = tid & 63, w = tid >> 6, l5 = lane & 31, hi = lane >> 5;
  int wr = w >> 1, wc = w & 1;
  f32x16 acc00, acc01, acc10, acc11;
#pragma unroll
  for (int i=0;i<16;++i){ acc00[i]=0.f; acc01[i]=0.f; acc10[i]=0.f; acc11[i]=0.f; }

  for (int kt=0; kt<8; ++kt){
    int k0 = kt*64;
    __syncthreads();
#pragma unroll
    for (int i=0;i<4;++i){
      int c = tid + i*256; int r = c>>3, cc = (c&7)*8;
      *(uint4*)&As[r][cc] = *(const uint4*)&A[(m0+r)*512 + k0 + cc];
    }
#pragma unroll
    for (int i=0;i<4;++i){
      int c = tid + i*256; int r = c>>3, cc = (c&7)*8;
      *(uint4*)&Bs[r][cc] = *(const uint4*)&BT[(n0+r)*512 + k0 + cc];
    }
    __syncthreads();
#pragma unroll
    for (int ks=0; ks<4; ++ks){
      bf16x8 a0 = *(const bf16x8*)&As[wr*64 + l5     ][ks*16 + hi*8];
      bf16x8 a1 = *(const bf16x8*)&As[wr*64 + 32 + l5][ks*16 + hi*8];
      bf16x8 b0 = *(const bf16x8*)&Bs[wc*64 + l5     ][ks*16 + hi*8];
      bf16x8 b1 = *(const bf16x8*)&Bs[wc*64 + 32 + l5][ks*16 + hi*8];
      acc00 = MFMA32(a0, b0, acc00, 0,0,0);
      acc01 = MFMA32(a0, b1, acc01, 0,0,0);
      acc10 = MFMA32(a1, b0, acc10, 0,0,0);
      acc11 = MFMA32(a1, b1, acc11, 0,0,0);
    }
  }
#pragma unroll
  for (int mt=0; mt<2; ++mt){
#pragma unroll
    for (int nt=0; nt<2; ++nt){
      const f32x16& acc = mt==0 ? (nt==0?acc00:acc01) : (nt==0?acc10:acc11);
      int n = n0 + wc*64 + nt*32 + l5;
      float bn = bias[n];
#pragma unroll
      for (int r=0;r<16;++r){
        int m = m0 + wr*64 + mt*32 + (r&3) + 8*(r>>2) + 4*hi;
        float v = acc[r] + bn;
        Cout[m*512 + n] = bf16r(fmaxf(v, 0.f) + bf2f(resid[m*512 + n]));
      }
    }
  }
}

// ---------------- flash attention, k-split x2, bf16 partials (R6 structure).
// bf16 mask-bias tile: LDS 42496 -> 39936 B => 4 blocks/CU (was 3).
// grid 1024: (b, 32-row q-tile, half of heads, k-split). 256 thr = 4 waves = 4 heads.
__global__ __launch_bounds__(256,4) void attn_kernel(
    const unsigned short* __restrict__ qb, const unsigned short* __restrict__ kb,
    const unsigned short* __restrict__ vt, const int* __restrict__ mask,
    unsigned short* __restrict__ Op, float* __restrict__ lbuf)
{
  int bid = blockIdx.x;
  int swz = (bid & 7)*128 + (bid >> 3);   // XCD-chunked swizzle (1024 % 8 == 0)
  int s  = swz & 1;                       // k-split half
  int hv = (swz >> 1) & 1;                // which half of the heads/channels
  int qt = (swz >> 2) & 63;
  int b  = swz >> 8;
  int q0 = qt * 32;

  __shared__ short Ks[32][264];           // K rows, 256-ch slice  (16896 B)
  __shared__ short Vs[256][40];           // V^T rows [d][k]       (20480 B)
  __shared__ unsigned short BiasB[64*20]; // mask bias bf16, C-frag layout (2560 B)

  int tid = threadIdx.x;
  int lane = tid & 63, w = tid >> 6, l5 = lane & 31, hi = lane >> 5;

  bf16x8 qf0, qf1, qf2, qf3;              // Q fragments (B-operand of S^T), hoisted
  {
    const unsigned short* qp = qb + (size_t)(b*2048 + q0 + l5)*512 + (hv*4 + w)*64 + hi*8;
    qf0 = *(const bf16x8*)(qp);
    qf1 = *(const bf16x8*)(qp + 16);
    qf2 = *(const bf16x8*)(qp + 32);
    qf3 = *(const bf16x8*)(qp + 48);
  }

  f32x16 o0, o1;
#pragma unroll
  for (int i=0;i<16;++i){ o0[i]=0.f; o1[i]=0.f; }
  float lsum = 0.f;

  const int kbeg = s*32, kend = s*32 + 32;
  const int kr0 = tid >> 5, kjc = (tid & 31)*8;
  const int vr0 = tid >> 2, vjc = (tid & 3)*8;
  const int qq = tid >> 3, kk4 = tid & 7;
  const unsigned short* kpb = kb + (size_t)(b*2048 + kr0)*512 + hv*256 + kjc;
  const unsigned short* vpb = vt + ((size_t)(b*64)*512 + hv*256)*32 + tid*8;
  const int* mpb = mask + (size_t)(b*2048 + q0 + qq)*2048 + kk4*4;

  uint4 rK0, rK1, rK2, rK3, rV0, rV1, rV2, rV3; int4 rM;
  {
    const unsigned short* kp = kpb + (size_t)kbeg*32*512;
    rK0 = *(const uint4*)(kp);
    rK1 = *(const uint4*)(kp + 8*512);
    rK2 = *(const uint4*)(kp + 16*512);
    rK3 = *(const uint4*)(kp + 24*512);
    const unsigned short* vp = vpb + (size_t)kbeg*512*32;
    rV0 = *(const uint4*)(vp);
    rV1 = *(const uint4*)(vp + 256*8);
    rV2 = *(const uint4*)(vp + 512*8);
    rV3 = *(const uint4*)(vp + 768*8);
    rM  = *(const int4*)(mpb + kbeg*32);
  }

  for (int kt=kbeg; kt<kend; ++kt){
    __syncthreads();
    *(uint4*)&Ks[kr0     ][kjc] = rK0;
    *(uint4*)&Ks[kr0 +  8][kjc] = rK1;
    *(uint4*)&Ks[kr0 + 16][kjc] = rK2;
    *(uint4*)&Ks[kr0 + 24][kjc] = rK3;
    *(uint4*)&Vs[vr0      ][vjc] = rV0;
    *(uint4*)&Vs[vr0 +  64][vjc] = rV1;
    *(uint4*)&Vs[vr0 + 128][vjc] = rV2;
    *(uint4*)&Vs[vr0 + 192][vjc] = rV3;
    {
      // bf16 bias: 0x0000 (keep) or 0xCEAC (== -1.44269504e9f exactly)
      uint2 bw;
      bw.x = (rM.x ? 0u : 0xCEACu) | (rM.y ? 0u : 0xCEAC0000u);
      bw.y = (rM.z ? 0u : 0xCEACu) | (rM.w ? 0u : 0xCEAC0000u);
      *(uint2*)&BiasB[(qq + (kk4&1)*32)*20 + ((kk4>>1)<<2)] = bw;
    }
    if (kt+1 < kend){
      const unsigned short* kp = kpb + (size_t)(kt+1)*32*512;
      rK0 = *(const uint4*)(kp);
      rK1 = *(const uint4*)(kp + 8*512);
      rK2 = *(const uint4*)(kp + 16*512);
      rK3 = *(const uint4*)(kp + 24*512);
      const unsigned short* vp = vpb + (size_t)(kt+1)*512*32;
      rV0 = *(const uint4*)(vp);
      rV1 = *(const uint4*)(vp + 256*8);
      rV2 = *(const uint4*)(vp + 512*8);
      rV3 = *(const uint4*)(vp + 768*8);
      rM  = *(const int4*)(mpb + (kt+1)*32);
    }
    __syncthreads();

    // S^T = K_tile @ Q_tile^T
    f32x16 sA;
#pragma unroll
    for (int i=0;i<16;++i) sA[i] = 0.f;
    __builtin_amdgcn_s_setprio(1);
    {
      bf16x8 kf;
      kf = *(const bf16x8*)&Ks[l5][w*64 +  0 + hi*8]; sA = MFMA32(kf, qf0, sA, 0,0,0);
      kf = *(const bf16x8*)&Ks[l5][w*64 + 16 + hi*8]; sA = MFMA32(kf, qf1, sA, 0,0,0);
      kf = *(const bf16x8*)&Ks[l5][w*64 + 32 + hi*8]; sA = MFMA32(kf, qf2, sA, 0,0,0);
      kf = *(const bf16x8*)&Ks[l5][w*64 + 48 + hi*8]; sA = MFMA32(kf, qf3, sA, 0,0,0);
    }
    __builtin_amdgcn_s_setprio(0);

    // p = exp2(s + bias)  -- raw v_exp_f32, bias unpacked from bf16 pairs
    float p0,p1,p2,p3,p4,p5,p6,p7,p8,p9,pa,pb,pc,pd,pe,pf;
    {
      uint2 bq0 = *(const uint2*)&BiasB[lane*20 + 0];
      p0 = fexp2(sA[0] + ubits(bq0.x << 16));
      p1 = fexp2(sA[1] + ubits(bq0.x & 0xFFFF0000u));
      p2 = fexp2(sA[2] + ubits(bq0.y << 16));
      p3 = fexp2(sA[3] + ubits(bq0.y & 0xFFFF0000u));
      uint2 bq1 = *(const uint2*)&BiasB[lane*20 + 4];
      p4 = fexp2(sA[4] + ubits(bq1.x << 16));
      p5 = fexp2(sA[5] + ubits(bq1.x & 0xFFFF0000u));
      p6 = fexp2(sA[6] + ubits(bq1.y << 16));
      p7 = fexp2(sA[7] + ubits(bq1.y & 0xFFFF0000u));
      uint2 bq2 = *(const uint2*)&BiasB[lane*20 + 8];
      p8 = fexp2(sA[8]  + ubits(bq2.x << 16));
      p9 = fexp2(sA[9]  + ubits(bq2.x & 0xFFFF0000u));
      pa = fexp2(sA[10] + ubits(bq2.y << 16));
      pb = fexp2(sA[11] + ubits(bq2.y & 0xFFFF0000u));
      uint2 bq3 = *(const uint2*)&BiasB[lane*20 + 12];
      pc = fexp2(sA[12] + ubits(bq3.x << 16));
      pd = fexp2(sA[13] + ubits(bq3.x & 0xFFFF0000u));
      pe = fexp2(sA[14] + ubits(bq3.y << 16));
      pf = fexp2(sA[15] + ubits(bq3.y & 0xFFFF0000u));
    }
    lsum += (((p0+p1)+(p2+p3)) + ((p4+p5)+(p6+p7))) +
            (((p8+p9)+(pa+pb)) + ((pc+pd)+(pe+pf)));

    unsigned a0w0 = cvtpk_bf16(p0, p1);
    unsigned a0w1 = cvtpk_bf16(p2, p3);
    unsigned a0w2 = cvtpk_bf16(p4, p5);
    unsigned a0w3 = cvtpk_bf16(p6, p7);
    permswap(a0w0, a0w2);
    permswap(a0w1, a0w3);
    unsigned a1w0 = cvtpk_bf16(p8, p9);
    unsigned a1w1 = cvtpk_bf16(pa, pb);
    unsigned a1w2 = cvtpk_bf16(pc, pd);
    unsigned a1w3 = cvtpk_bf16(pe, pf);
    permswap(a1w0, a1w2);
    permswap(a1w1, a1w3);
    uint4 u0; u0.x = a0w0; u0.y = a0w1; u0.z = a0w2; u0.w = a0w3;
    uint4 u1; u1.x = a1w0; u1.y = a1w1; u1.z = a1w2; u1.w = a1w3;
    bf16x8 pa0 = __builtin_bit_cast(bf16x8, u0);
    bf16x8 pa1 = __builtin_bit_cast(bf16x8, u1);

    bf16x8 v00 = *(const bf16x8*)&Vs[w*64      + l5][hi*8];
    bf16x8 v01 = *(const bf16x8*)&Vs[w*64      + l5][16 + hi*8];
    bf16x8 v10 = *(const bf16x8*)&Vs[w*64 + 32 + l5][hi*8];
    bf16x8 v11 = *(const bf16x8*)&Vs[w*64 + 32 + l5][16 + hi*8];
    __builtin_amdgcn_s_setprio(1);
    o0 = MFMA32(pa0, v00, o0, 0,0,0);
    o0 = MFMA32(pa1, v01, o0, 0,0,0);
    o1 = MFMA32(pa0, v10, o1, 0,0,0);
    o1 = MFMA32(pa1, v11, o1, 0,0,0);
    __builtin_amdgcn_s_setprio(0);
  }

  float lfull = lsum + __shfl_xor(lsum, 32, 64);
  if (hi == 0){
    lbuf[(size_t)(b*2048 + q0 + l5)*16 + s*8 + (hv*4 + w)] = lfull;
  }
  unsigned short* op = Op + (size_t)s * 4194304u;
#pragma unroll
  for (int nt=0; nt<2; ++nt){
#pragma unroll
    for (int r=0;r<16;++r){
      int qlocal = (r&3) + 8*(r>>2) + 4*hi;
      int q = q0 + qlocal;
      int d = hv*256 + w*64 + nt*32 + l5;
      op[(size_t)(b*2048 + q)*512 + d] = bf16r(nt==0 ? o0[r] : o1[r]);
    }
  }
}

// ---------------- combine partials + divide + residual + LayerNorm0 -> bf16
__global__ __launch_bounds__(256) void combine_ln_kernel(
    const unsigned short* __restrict__ OpA, const unsigned short* __restrict__ OpB,
    const float* __restrict__ lbuf, const unsigned short* __restrict__ qb,
    const float* __restrict__ g, const float* __restrict__ be,
    unsigned short* __restrict__ Y)
{
  int row = blockIdx.x*4 + (threadIdx.x >> 6);
  int lane = threadIdx.x & 63;
  int h = lane >> 3;
  float lA = lbuf[(size_t)row*16 + h];
  float lB = lbuf[(size_t)row*16 + 8 + h];
  float inv = __builtin_amdgcn_rcpf(lA + lB);
  size_t base = (size_t)row*512 + lane*8;
  bf16x8 a  = *(const bf16x8*)&OpA[base];
  bf16x8 bb = *(const bf16x8*)&OpB[base];
  bf16x8 qv = *(const bf16x8*)&qb[base];
  float x0 = (bf2f((unsigned short)a[0]) + bf2f((unsigned short)bb[0]))*inv + bf2f((unsigned short)qv[0]);
  float x1 = (bf2f((unsigned short)a[1]) + bf2f((unsigned short)bb[1]))*inv + bf2f((unsigned short)qv[1]);
  float x2 = (bf2f((unsigned short)a[2]) + bf2f((unsigned short)bb[2]))*inv + bf2f((unsigned short)qv[2]);
  float x3 = (bf2f((unsigned short)a[3]) + bf2f((unsigned short)bb[3]))*inv + bf2f((unsigned short)qv[3]);
  float x4 = (bf2f((unsigned short)a[4]) + bf2f((unsigned short)bb[4]))*inv + bf2f((unsigned short)qv[4]);
  float x5 = (bf2f((unsigned short)a[5]) + bf2f((unsigned short)bb[5]))*inv + bf2f((unsigned short)qv[5]);
  float x6 = (bf2f((unsigned short)a[6]) + bf2f((unsigned short)bb[6]))*inv + bf2f((unsigned short)qv[6]);
  float x7 = (bf2f((unsigned short)a[7]) + bf2f((unsigned short)bb[7]))*inv + bf2f((unsigned short)qv[7]);
  float sm = ((x0+x1)+(x2+x3)) + ((x4+x5)+(x6+x7));
#pragma unroll
  for (int m=1; m<64; m<<=1) sm += __shfl_xor(sm, m, 64);
  float mean = sm * (1.0f/512.0f);
  float d0=x0-mean, d1=x1-mean, d2=x2-mean, d3=x3-mean;
  float d4=x4-mean, d5=x5-mean, d6=x6-mean, d7=x7-mean;
  float s2 = ((d0*d0+d1*d1)+(d2*d2+d3*d3)) + ((d4*d4+d5*d5)+(d6*d6+d7*d7));
#pragma unroll
  for (int m=1; m<64; m<<=1) s2 += __shfl_xor(s2, m, 64);
  float rstd = rsqrtf(s2*(1.0f/512.0f) + 1e-5f);
  const float* gp = g + lane*8; const float* bp = be + lane*8;
  float4 g0 = *(const float4*)gp, g1 = *(const float4*)(gp+4);
  float4 b0 = *(const float4*)bp, b1 = *(const float4*)(bp+4);
  uint4 yo;
  yo.x = bfpack2(d0*rstd*g0.x + b0.x, d1*rstd*g0.y + b0.y);
  yo.y = bfpack2(d2*rstd*g0.z + b0.z, d3*rstd*g0.w + b0.w);
  yo.z = bfpack2(d4*rstd*g1.x + b1.x, d5*rstd*g1.y + b1.y);
  yo.w = bfpack2(d6*rstd*g1.z + b1.z, d7*rstd*g1.w + b1.w);
  *(uint4*)&Y[base] = yo;
}

// ---------------- LayerNorm over 512 reading bf16, 4 rows/block, writes f32
__global__ __launch_bounds__(256) void ln_bf16_kernel(
    const unsigned short* __restrict__ X, const float* __restrict__ g,
    const float* __restrict__ be, float* __restrict__ Y)
{
  int row = blockIdx.x*4 + (threadIdx.x >> 6);
  int lane = threadIdx.x & 63;
  size_t base = (size_t)row*512 + lane*8;
  bf16x8 xv = *(const bf16x8*)&X[base];
  float x0 = bf2f((unsigned short)xv[0]), x1 = bf2f((unsigned short)xv[1]);
  float x2 = bf2f((unsigned short)xv[2]), x3 = bf2f((unsigned short)xv[3]);
  float x4 = bf2f((unsigned short)xv[4]), x5 = bf2f((unsigned short)xv[5]);
  float x6 = bf2f((unsigned short)xv[6]), x7 = bf2f((unsigned short)xv[7]);
  float s = ((x0+x1)+(x2+x3)) + ((x4+x5)+(x6+x7));
#pragma unroll
  for (int m=1; m<64; m<<=1) s += __shfl_xor(s, m, 64);
  float mean = s * (1.0f/512.0f);
  float d0=x0-mean, d1=x1-mean, d2=x2-mean, d3=x3-mean;
  float d4=x4-mean, d5=x5-mean, d6=x6-mean, d7=x7-mean;
  float s2 = ((d0*d0+d1*d1)+(d2*d2+d3*d3)) + ((d4*d4+d5*d5)+(d6*d6+d7*d7));
#pragma unroll
  for (int m=1; m<64; m<<=1) s2 += __shfl_xor(s2, m, 64);
  float rstd = rsqrtf(s2*(1.0f/512.0f) + 1e-5f);
  const float* gp = g + lane*8; const float* bp = be + lane*8;
  float4 g0 = *(const float4*)gp, g1 = *(const float4*)(gp+4);
  float4 b0 = *(const float4*)bp, b1 = *(const float4*)(bp+4);
  float4 y0, y1;
  y0.x = d0*rstd*g0.x + b0.x; y0.y = d1*rstd*g0.y + b0.y;
  y0.z = d2*rstd*g0.z + b0.z; y0.w = d3*rstd*g0.w + b0.w;
  y1.x = d4*rstd*g1.x + b1.x; y1.y = d5*rstd*g1.y + b1.y;
  y1.z = d6*rstd*g1.z + b1.z; y1.w = d7*rstd*g1.w + b1.w;
  float* yp = Y + base;
  *(float4*)yp = y0;
  *(float4*)(yp+4) = y1;
}

extern "C" void kernel_launch(void* const* d_in, const int* in_sizes, int n_in,
                              void* d_out, int out_size, void* d_ws, size_t ws_size,
                              hipStream_t stream) {
  const float* Q    = (const float*)d_in[0];
  const float* K    = (const float*)d_in[1];
  const int*   mask = (const int*)d_in[2];
  const float* temp = (const float*)d_in[3];
  const float* Wq = (const float*)d_in[4];  const float* bq = (const float*)d_in[5];
  const float* Wk = (const float*)d_in[6];  const float* bk = (const float*)d_in[7];
  const float* Wv = (const float*)d_in[8];  const float* bv = (const float*)d_in[9];
  const float* Wo = (const float*)d_in[10]; const float* bo = (const float*)d_in[11];
  const float* g0 = (const float*)d_in[12]; const float* b0 = (const float*)d_in[13];
  const float* g1 = (const float*)d_in[14]; const float* b1 = (const float*)d_in[15];
  float* out = (float*)d_out;
  (void)in_sizes; (void)n_in; (void)out_size; (void)ws_size;

  char* ws = (char*)d_ws;
  unsigned short* qbuf = (unsigned short*)(ws + 0);          // 8.4MB  q proj (bf16)
  unsigned short* kbuf = (unsigned short*)(ws + 8388608);    // 8.4MB  k proj (scaled)
  unsigned short* vtb  = (unsigned short*)(ws + 16777216);   // 8.4MB  v tile-major
  unsigned short* OpA  = (unsigned short*)(ws + 25165824);   // 2x 8.4MB bf16 partials
  unsigned short* WqT  = (unsigned short*)(ws + 41943040);   // 4 x 0.5MB
  unsigned short* WkT  = WqT + 262144;
  unsigned short* WvT  = WqT + 524288;
  unsigned short* WoT  = WqT + 786432;
  float* lbuf = (float*)(ws + 44040192);                     // 512KB per-(row,split,head) sums
  unsigned short* Olnf = (unsigned short*)(ws + 8388608);    // 8.4MB post-LN0 bf16 (alias kbuf)
  unsigned short* O2   = (unsigned short*)(ws + 25165824);   // 8.4MB post-GEMM bf16 (alias OpA)

  wt_kernel<<<dim3(8,8,4), 256, 0, stream>>>(Wq, Wk, Wv, Wo, WqT, WkT, WvT, WoT);
  qkv_kernel<<<dim3(64,4,3), 256, 0, stream>>>(Q, K, WqT, WkT, WvT, bq, bk, bv, temp,
                                               qbuf, kbuf, vtb);
  attn_kernel<<<1024, 256, 0, stream>>>(qbuf, kbuf, vtb, mask, OpA, lbuf);
  combine_ln_kernel<<<2048, 256, 0, stream>>>(OpA, OpA + 4194304, lbuf, qbuf, g0, b0, Olnf);
  gemm_o_kernel<<<dim3(64,4), 256, 0, stream>>>(Olnf, WoT, bo, O2, Olnf);
  ln_bf16_kernel<<<2048, 256, 0, stream>>>(O2, g1, b1, out);
}

// Round 15
// 142.159 us; speedup vs baseline: 1.1880x; 1.1880x over previous
//
#include <hip/hip_runtime.h>

typedef __attribute__((ext_vector_type(8))) short bf16x8;
typedef __attribute__((ext_vector_type(16))) float f32x16;

#define MFMA32 __builtin_amdgcn_mfma_f32_32x32x16_bf16

__device__ __forceinline__ unsigned short bf16r(float f){
  unsigned u = __builtin_bit_cast(unsigned, f);
  unsigned r = (u + 0x7FFFu + ((u >> 16) & 1u)) >> 16;
  return (unsigned short)r;
}
__device__ __forceinline__ unsigned bfpack2(float a, float b){
  unsigned ua = __builtin_bit_cast(unsigned, a);
  unsigned ub = __builtin_bit_cast(unsigned, b);
  unsigned ra = (ua + 0x7FFFu + ((ua >> 16) & 1u)) >> 16;
  unsigned rb = (ub + 0x7FFFu + ((ub >> 16) & 1u)) & 0xFFFF0000u;
  return (ra & 0xFFFFu) | rb;
}
__device__ __forceinline__ float bf2f(unsigned short h){
  unsigned u = ((unsigned)h) << 16;
  return __builtin_bit_cast(float, u);
}
__device__ __forceinline__ unsigned cvtpk_bf16(float a, float b){
  unsigned r;
  asm("v_cvt_pk_bf16_f32 %0, %1, %2" : "=v"(r) : "v"(a), "v"(b));
  return r;
}
__device__ __forceinline__ void permswap(unsigned &x, unsigned &y){
  asm volatile("v_permlane32_swap_b32 %0, %1" : "+v"(x), "+v"(y));
}
__device__ __forceinline__ float fexp2(float x){     // raw v_exp_f32 (2^x)
  float r; asm("v_exp_f32 %0, %1" : "=v"(r) : "v"(x)); return r;
}

// ---------------- weight transpose: W[k][n] f32 -> WT[n][k] bf16 (512x512, 4 mats)
__global__ __launch_bounds__(256) void wt_kernel(
    const float* __restrict__ W0, const float* __restrict__ W1,
    const float* __restrict__ W2, const float* __restrict__ W3,
    unsigned short* __restrict__ T0, unsigned short* __restrict__ T1,
    unsigned short* __restrict__ T2, unsigned short* __restrict__ T3)
{
  int z = blockIdx.z;
  const float* W = z==0?W0 : z==1?W1 : z==2?W2 : W3;
  unsigned short* T = z==0?T0 : z==1?T1 : z==2?T2 : T3;
  __shared__ float tile[64][68];
  int kb0 = blockIdx.x*64, nb0 = blockIdx.y*64;
  int tid = threadIdx.x;
#pragma unroll
  for (int i=0;i<4;++i){
    int c = tid + i*256; int r = c>>4, cc = (c&15)*4;
    *(float4*)&tile[r][cc] = *(const float4*)&W[(kb0+r)*512 + nb0 + cc];
  }
  __syncthreads();
#pragma unroll
  for (int i=0;i<4;++i){
    int c = tid + i*256; int o = c*4; int n = o>>6, kk = o&63;
    ushort4 pk;
    pk.x = bf16r(tile[kk+0][n]); pk.y = bf16r(tile[kk+1][n]);
    pk.z = bf16r(tile[kk+2][n]); pk.w = bf16r(tile[kk+3][n]);
    *(ushort4*)&T[(nb0+n)*512 + kb0 + kk] = pk;
  }
}

// ---------------- fused QKV projection. grid (64,4,3).
// z=0: q = Q@Wq+bq           -> qbuf (bf16)
// z=1: k = (K@Wk+bk)*scale_m -> kbuf (bf16), scale_m = log2e/(sqrt(512)*temp[m])
// z=2: v = K@Wv+bv           -> vt (bf16, tile-major [b][kt32][d][kk32]) via LDS transpose
__global__ __launch_bounds__(256,2) void qkv_kernel(
    const float* __restrict__ Qin, const float* __restrict__ Kin,
    const unsigned short* __restrict__ WqT, const unsigned short* __restrict__ WkT,
    const unsigned short* __restrict__ WvT,
    const float* __restrict__ bq, const float* __restrict__ bk,
    const float* __restrict__ bv, const float* __restrict__ temp,
    unsigned short* __restrict__ qbuf, unsigned short* __restrict__ kbuf,
    unsigned short* __restrict__ vt)
{
  const float RS2K = 0.044194173824159216f * 1.4426950408889634f;
  __shared__ short SM[128*144];                    // As|Bs, reused as Lt[128][144]
  short (*As)[72] = (short(*)[72])SM;
  short (*Bs)[72] = (short(*)[72])(SM + 128*72);
  int z = blockIdx.z;
  const float* A = (z==0) ? Qin : Kin;
  const unsigned short* BT = z==0 ? WqT : (z==1 ? WkT : WvT);
  const float* bias = z==0 ? bq : (z==1 ? bk : bv);
  int m0 = blockIdx.x*128, n0 = blockIdx.y*128;
  int tid = threadIdx.x;
  int lane = tid & 63, w = tid >> 6, l5 = lane & 31, hi = lane >> 5;
  int wr = w >> 1, wc = w & 1;
  f32x16 acc00, acc01, acc10, acc11;
#pragma unroll
  for (int i=0;i<16;++i){ acc00[i]=0.f; acc01[i]=0.f; acc10[i]=0.f; acc11[i]=0.f; }

  for (int kt=0; kt<8; ++kt){
    int k0 = kt*64;
    __syncthreads();
#pragma unroll
    for (int i=0;i<4;++i){
      int c = tid + i*256; int r = c>>3, cc = (c&7)*8;
      const float* src = &A[(m0+r)*512 + k0 + cc];
      float4 v0 = *(const float4*)src;
      float4 v1 = *(const float4*)(src+4);
      uint4 pk;
      pk.x = bfpack2(v0.x, v0.y); pk.y = bfpack2(v0.z, v0.w);
      pk.z = bfpack2(v1.x, v1.y); pk.w = bfpack2(v1.z, v1.w);
      *(uint4*)&As[r][cc] = pk;
    }
#pragma unroll
    for (int i=0;i<4;++i){
      int c = tid + i*256; int r = c>>3, cc = (c&7)*8;
      *(uint4*)&Bs[r][cc] = *(const uint4*)&BT[(n0+r)*512 + k0 + cc];
    }
    __syncthreads();
#pragma unroll
    for (int ks=0; ks<4; ++ks){
      bf16x8 a0 = *(const bf16x8*)&As[wr*64 + l5     ][ks*16 + hi*8];
      bf16x8 a1 = *(const bf16x8*)&As[wr*64 + 32 + l5][ks*16 + hi*8];
      bf16x8 b0 = *(const bf16x8*)&Bs[wc*64 + l5     ][ks*16 + hi*8];
      bf16x8 b1 = *(const bf16x8*)&Bs[wc*64 + 32 + l5][ks*16 + hi*8];
      acc00 = MFMA32(a0, b0, acc00, 0,0,0);
      acc01 = MFMA32(a0, b1, acc01, 0,0,0);
      acc10 = MFMA32(a1, b0, acc10, 0,0,0);
      acc11 = MFMA32(a1, b1, acc11, 0,0,0);
    }
  }

  if (z <= 1){
    unsigned short* Cout = (z==0) ? qbuf : kbuf;
#pragma unroll
    for (int mt=0; mt<2; ++mt){
      float sc[16];
      if (z==1){
        int mb = m0 + wr*64 + mt*32 + 4*hi;
#pragma unroll
        for (int qd=0; qd<4; ++qd)
#pragma unroll
        for (int j=0; j<4; ++j)
          sc[qd*4+j] = RS2K*__builtin_amdgcn_rcpf(temp[mb + qd*8 + j]);
      }
#pragma unroll
      for (int nt=0; nt<2; ++nt){
        const f32x16& acc = mt==0 ? (nt==0?acc00:acc01) : (nt==0?acc10:acc11);
        int n = n0 + wc*64 + nt*32 + l5;
        float bn = bias[n];
#pragma unroll
        for (int r=0;r<16;++r){
          int m = m0 + wr*64 + mt*32 + (r&3) + 8*(r>>2) + 4*hi;
          float v = acc[r] + bn;
          if (z==1) v *= sc[r];
          Cout[m*512 + n] = bf16r(v);
        }
      }
    }
  } else {
    // ---- V: transpose via LDS, store tile-major
    __syncthreads();                       // done reading As/Bs
    short* Lt = SM;                        // [128 n][144 m-stride]
#pragma unroll
    for (int mt=0; mt<2; ++mt)
#pragma unroll
    for (int nt=0; nt<2; ++nt){
      const f32x16& acc = mt==0 ? (nt==0?acc00:acc01) : (nt==0?acc10:acc11);
      int n = wc*64 + nt*32 + l5;
      float bn = bias[n0 + n];
#pragma unroll
      for (int qd=0; qd<4; ++qd){
        int mloc = wr*64 + mt*32 + qd*8 + 4*hi;
        uint2 pk;
        pk.x = bfpack2(acc[qd*4+0]+bn, acc[qd*4+1]+bn);
        pk.y = bfpack2(acc[qd*4+2]+bn, acc[qd*4+3]+bn);
        *(uint2*)&Lt[n*144 + mloc] = pk;
      }
    }
    __syncthreads();
    int b = m0 >> 11;
    int ktb = (m0 & 2047) >> 5;
#pragma unroll
    for (int pass=0; pass<2; ++pass){
      int d = (tid>>2) + pass*64;
      int kk0 = (tid&3)*8;
#pragma unroll
      for (int kt=0; kt<4; ++kt){
        uint4 v = *(const uint4*)&Lt[d*144 + kt*32 + kk0];
        *(uint4*)&vt[(size_t)((b*64 + ktb + kt)*512 + n0 + d)*32 + kk0] = v;
      }
    }
  }
}

// ---------------- GEMM (O-projection): C = relu(A@W + bias) + resid -> bf16
__global__ __launch_bounds__(256,2) void gemm_o_kernel(
    const unsigned short* __restrict__ A, const unsigned short* __restrict__ BT,
    const float* __restrict__ bias, unsigned short* __restrict__ Cout,
    const unsigned short* __restrict__ resid)
{
  __shared__ short As[128][72];
  __shared__ short Bs[128][72];
  int m0 = blockIdx.x*128, n0 = blockIdx.y*128;
  int tid = threadIdx.x;
  int lane = tid & 63, w = tid >> 6, l5 = lane & 31, hi = lane >> 5;
  int wr = w >> 1, wc = w & 1;
  f32x16 acc00, acc01, acc10, acc11;
#pragma unroll
  for (int i=0;i<16;++i){ acc00[i]=0.f; acc01[i]=0.f; acc10[i]=0.f; acc11[i]=0.f; }

  for (int kt=0; kt<8; ++kt){
    int k0 = kt*64;
    __syncthreads();
#pragma unroll
    for (int i=0;i<4;++i){
      int c = tid + i*256; int r = c>>3, cc = (c&7)*8;
      *(uint4*)&As[r][cc] = *(const uint4*)&A[(m0+r)*512 + k0 + cc];
    }
#pragma unroll
    for (int i=0;i<4;++i){
      int c = tid + i*256; int r = c>>3, cc = (c&7)*8;
      *(uint4*)&Bs[r][cc] = *(const uint4*)&BT[(n0+r)*512 + k0 + cc];
    }
    __syncthreads();
#pragma unroll
    for (int ks=0; ks<4; ++ks){
      bf16x8 a0 = *(const bf16x8*)&As[wr*64 + l5     ][ks*16 + hi*8];
      bf16x8 a1 = *(const bf16x8*)&As[wr*64 + 32 + l5][ks*16 + hi*8];
      bf16x8 b0 = *(const bf16x8*)&Bs[wc*64 + l5     ][ks*16 + hi*8];
      bf16x8 b1 = *(const bf16x8*)&Bs[wc*64 + 32 + l5][ks*16 + hi*8];
      acc00 = MFMA32(a0, b0, acc00, 0,0,0);
      acc01 = MFMA32(a0, b1, acc01, 0,0,0);
      acc10 = MFMA32(a1, b0, acc10, 0,0,0);
      acc11 = MFMA32(a1, b1, acc11, 0,0,0);
    }
  }
#pragma unroll
  for (int mt=0; mt<2; ++mt){
#pragma unroll
    for (int nt=0; nt<2; ++nt){
      const f32x16& acc = mt==0 ? (nt==0?acc00:acc01) : (nt==0?acc10:acc11);
      int n = n0 + wc*64 + nt*32 + l5;
      float bn = bias[n];
#pragma unroll
      for (int r=0;r<16;++r){
        int m = m0 + wr*64 + mt*32 + (r&3) + 8*(r>>2) + 4*hi;
        float v = acc[r] + bn;
        Cout[m*512 + n] = bf16r(fmaxf(v, 0.f) + bf2f(resid[m*512 + n]));
      }
    }
  }
}

// ---------------- flash attention, k-split x2, bf16 partials (R6 structure, proven).
// Scale pre-folded into K. Reg-prefetch pipeline + in-register P + setprio + raw v_exp.
// grid 1024: (b, 32-row q-tile, half of heads, k-split). 256 thr = 4 waves = 4 heads.
__global__ __launch_bounds__(256,3) void attn_kernel(
    const unsigned short* __restrict__ qb, const unsigned short* __restrict__ kb,
    const unsigned short* __restrict__ vt, const int* __restrict__ mask,
    unsigned short* __restrict__ Op, float* __restrict__ lbuf)
{
  int bid = blockIdx.x;
  int swz = (bid & 7)*128 + (bid >> 3);   // XCD-chunked swizzle (1024 % 8 == 0)
  int s  = swz & 1;                       // k-split half
  int hv = (swz >> 1) & 1;                // which half of the heads/channels
  int qt = (swz >> 2) & 63;
  int b  = swz >> 8;
  int q0 = qt * 32;

  __shared__ short Ks[32][264];           // K rows, 256-ch slice, stride 132w
  __shared__ short Vs[256][40];           // V^T rows [d][k], stride 20w
  __shared__ float BiasF[64*20];          // mask bias in C-frag layout

  int tid = threadIdx.x;
  int lane = tid & 63, w = tid >> 6, l5 = lane & 31, hi = lane >> 5;

  bf16x8 qf0, qf1, qf2, qf3;              // Q fragments (B-operand of S^T), hoisted
  {
    const unsigned short* qp = qb + (size_t)(b*2048 + q0 + l5)*512 + (hv*4 + w)*64 + hi*8;
    qf0 = *(const bf16x8*)(qp);
    qf1 = *(const bf16x8*)(qp + 16);
    qf2 = *(const bf16x8*)(qp + 32);
    qf3 = *(const bf16x8*)(qp + 48);
  }

  f32x16 o0, o1;
#pragma unroll
  for (int i=0;i<16;++i){ o0[i]=0.f; o1[i]=0.f; }
  float lsum = 0.f;

  const int kbeg = s*32, kend = s*32 + 32;
  const int kr0 = tid >> 5, kjc = (tid & 31)*8;
  const int vr0 = tid >> 2, vjc = (tid & 3)*8;
  const int qq = tid >> 3, kk4 = tid & 7;
  const unsigned short* kpb = kb + (size_t)(b*2048 + kr0)*512 + hv*256 + kjc;
  const unsigned short* vpb = vt + ((size_t)(b*64)*512 + hv*256)*32 + tid*8;
  const int* mpb = mask + (size_t)(b*2048 + q0 + qq)*2048 + kk4*4;

  uint4 rK0, rK1, rK2, rK3, rV0, rV1, rV2, rV3; int4 rM;
  {
    const unsigned short* kp = kpb + (size_t)kbeg*32*512;
    rK0 = *(const uint4*)(kp);
    rK1 = *(const uint4*)(kp + 8*512);
    rK2 = *(const uint4*)(kp + 16*512);
    rK3 = *(const uint4*)(kp + 24*512);
    const unsigned short* vp = vpb + (size_t)kbeg*512*32;
    rV0 = *(const uint4*)(vp);
    rV1 = *(const uint4*)(vp + 256*8);
    rV2 = *(const uint4*)(vp + 512*8);
    rV3 = *(const uint4*)(vp + 768*8);
    rM  = *(const int4*)(mpb + kbeg*32);
  }

  for (int kt=kbeg; kt<kend; ++kt){
    __syncthreads();
    *(uint4*)&Ks[kr0     ][kjc] = rK0;
    *(uint4*)&Ks[kr0 +  8][kjc] = rK1;
    *(uint4*)&Ks[kr0 + 16][kjc] = rK2;
    *(uint4*)&Ks[kr0 + 24][kjc] = rK3;
    *(uint4*)&Vs[vr0      ][vjc] = rV0;
    *(uint4*)&Vs[vr0 +  64][vjc] = rV1;
    *(uint4*)&Vs[vr0 + 128][vjc] = rV2;
    *(uint4*)&Vs[vr0 + 192][vjc] = rV3;
    {
      float4 bw;
      bw.x = rM.x ? 0.f : -1.44269504e9f;
      bw.y = rM.y ? 0.f : -1.44269504e9f;
      bw.z = rM.z ? 0.f : -1.44269504e9f;
      bw.w = rM.w ? 0.f : -1.44269504e9f;
      *(float4*)&BiasF[(qq + (kk4&1)*32)*20 + ((kk4>>1)<<2)] = bw;
    }
    if (kt+1 < kend){
      const unsigned short* kp = kpb + (size_t)(kt+1)*32*512;
      rK0 = *(const uint4*)(kp);
      rK1 = *(const uint4*)(kp + 8*512);
      rK2 = *(const uint4*)(kp + 16*512);
      rK3 = *(const uint4*)(kp + 24*512);
      const unsigned short* vp = vpb + (size_t)(kt+1)*512*32;
      rV0 = *(const uint4*)(vp);
      rV1 = *(const uint4*)(vp + 256*8);
      rV2 = *(const uint4*)(vp + 512*8);
      rV3 = *(const uint4*)(vp + 768*8);
      rM  = *(const int4*)(mpb + (kt+1)*32);
    }
    __syncthreads();

    // S^T = K_tile @ Q_tile^T
    f32x16 sA;
#pragma unroll
    for (int i=0;i<16;++i) sA[i] = 0.f;
    __builtin_amdgcn_s_setprio(1);
    {
      bf16x8 kf;
      kf = *(const bf16x8*)&Ks[l5][w*64 +  0 + hi*8]; sA = MFMA32(kf, qf0, sA, 0,0,0);
      kf = *(const bf16x8*)&Ks[l5][w*64 + 16 + hi*8]; sA = MFMA32(kf, qf1, sA, 0,0,0);
      kf = *(const bf16x8*)&Ks[l5][w*64 + 32 + hi*8]; sA = MFMA32(kf, qf2, sA, 0,0,0);
      kf = *(const bf16x8*)&Ks[l5][w*64 + 48 + hi*8]; sA = MFMA32(kf, qf3, sA, 0,0,0);
    }
    __builtin_amdgcn_s_setprio(0);

    // p = exp2(s + bias)  -- raw v_exp_f32
    float p0,p1,p2,p3,p4,p5,p6,p7,p8,p9,pa,pb,pc,pd,pe,pf;
    {
      float4 bq0 = *(const float4*)&BiasF[lane*20 + 0];
      p0 = fexp2(sA[0] + bq0.x);
      p1 = fexp2(sA[1] + bq0.y);
      p2 = fexp2(sA[2] + bq0.z);
      p3 = fexp2(sA[3] + bq0.w);
      float4 bq1 = *(const float4*)&BiasF[lane*20 + 4];
      p4 = fexp2(sA[4] + bq1.x);
      p5 = fexp2(sA[5] + bq1.y);
      p6 = fexp2(sA[6] + bq1.z);
      p7 = fexp2(sA[7] + bq1.w);
      float4 bq2 = *(const float4*)&BiasF[lane*20 + 8];
      p8 = fexp2(sA[8]  + bq2.x);
      p9 = fexp2(sA[9]  + bq2.y);
      pa = fexp2(sA[10] + bq2.z);
      pb = fexp2(sA[11] + bq2.w);
      float4 bq3 = *(const float4*)&BiasF[lane*20 + 12];
      pc = fexp2(sA[12] + bq3.x);
      pd = fexp2(sA[13] + bq3.y);
      pe = fexp2(sA[14] + bq3.z);
      pf = fexp2(sA[15] + bq3.w);
    }
    lsum += (((p0+p1)+(p2+p3)) + ((p4+p5)+(p6+p7))) +
            (((p8+p9)+(pa+pb)) + ((pc+pd)+(pe+pf)));

    unsigned a0w0 = cvtpk_bf16(p0, p1);
    unsigned a0w1 = cvtpk_bf16(p2, p3);
    unsigned a0w2 = cvtpk_bf16(p4, p5);
    unsigned a0w3 = cvtpk_bf16(p6, p7);
    permswap(a0w0, a0w2);
    permswap(a0w1, a0w3);
    unsigned a1w0 = cvtpk_bf16(p8, p9);
    unsigned a1w1 = cvtpk_bf16(pa, pb);
    unsigned a1w2 = cvtpk_bf16(pc, pd);
    unsigned a1w3 = cvtpk_bf16(pe, pf);
    permswap(a1w0, a1w2);
    permswap(a1w1, a1w3);
    uint4 u0; u0.x = a0w0; u0.y = a0w1; u0.z = a0w2; u0.w = a0w3;
    uint4 u1; u1.x = a1w0; u1.y = a1w1; u1.z = a1w2; u1.w = a1w3;
    bf16x8 pa0 = __builtin_bit_cast(bf16x8, u0);
    bf16x8 pa1 = __builtin_bit_cast(bf16x8, u1);

    bf16x8 v00 = *(const bf16x8*)&Vs[w*64      + l5][hi*8];
    bf16x8 v01 = *(const bf16x8*)&Vs[w*64      + l5][16 + hi*8];
    bf16x8 v10 = *(const bf16x8*)&Vs[w*64 + 32 + l5][hi*8];
    bf16x8 v11 = *(const bf16x8*)&Vs[w*64 + 32 + l5][16 + hi*8];
    __builtin_amdgcn_s_setprio(1);
    o0 = MFMA32(pa0, v00, o0, 0,0,0);
    o0 = MFMA32(pa1, v01, o0, 0,0,0);
    o1 = MFMA32(pa0, v10, o1, 0,0,0);
    o1 = MFMA32(pa1, v11, o1, 0,0,0);
    __builtin_amdgcn_s_setprio(0);
  }

  float lfull = lsum + __shfl_xor(lsum, 32, 64);
  if (hi == 0){
    lbuf[(size_t)(b*2048 + q0 + l5)*16 + s*8 + (hv*4 + w)] = lfull;
  }
  unsigned short* op = Op + (size_t)s * 4194304u;
#pragma unroll
  for (int nt=0; nt<2; ++nt){
#pragma unroll
    for (int r=0;r<16;++r){
      int qlocal = (r&3) + 8*(r>>2) + 4*hi;
      int q = q0 + qlocal;
      int d = hv*256 + w*64 + nt*32 + l5;
      op[(size_t)(b*2048 + q)*512 + d] = bf16r(nt==0 ? o0[r] : o1[r]);
    }
  }
}

// ---------------- combine partials + divide + residual + LayerNorm0 -> bf16
__global__ __launch_bounds__(256) void combine_ln_kernel(
    const unsigned short* __restrict__ OpA, const unsigned short* __restrict__ OpB,
    const float* __restrict__ lbuf, const unsigned short* __restrict__ qb,
    const float* __restrict__ g, const float* __restrict__ be,
    unsigned short* __restrict__ Y)
{
  int row = blockIdx.x*4 + (threadIdx.x >> 6);
  int lane = threadIdx.x & 63;
  int h = lane >> 3;
  float lA = lbuf[(size_t)row*16 + h];
  float lB = lbuf[(size_t)row*16 + 8 + h];
  float inv = __builtin_amdgcn_rcpf(lA + lB);
  size_t base = (size_t)row*512 + lane*8;
  bf16x8 a  = *(const bf16x8*)&OpA[base];
  bf16x8 bb = *(const bf16x8*)&OpB[base];
  bf16x8 qv = *(const bf16x8*)&qb[base];
  float x0 = (bf2f((unsigned short)a[0]) + bf2f((unsigned short)bb[0]))*inv + bf2f((unsigned short)qv[0]);
  float x1 = (bf2f((unsigned short)a[1]) + bf2f((unsigned short)bb[1]))*inv + bf2f((unsigned short)qv[1]);
  float x2 = (bf2f((unsigned short)a[2]) + bf2f((unsigned short)bb[2]))*inv + bf2f((unsigned short)qv[2]);
  float x3 = (bf2f((unsigned short)a[3]) + bf2f((unsigned short)bb[3]))*inv + bf2f((unsigned short)qv[3]);
  float x4 = (bf2f((unsigned short)a[4]) + bf2f((unsigned short)bb[4]))*inv + bf2f((unsigned short)qv[4]);
  float x5 = (bf2f((unsigned short)a[5]) + bf2f((unsigned short)bb[5]))*inv + bf2f((unsigned short)qv[5]);
  float x6 = (bf2f((unsigned short)a[6]) + bf2f((unsigned short)bb[6]))*inv + bf2f((unsigned short)qv[6]);
  float x7 = (bf2f((unsigned short)a[7]) + bf2f((unsigned short)bb[7]))*inv + bf2f((unsigned short)qv[7]);
  float sm = ((x0+x1)+(x2+x3)) + ((x4+x5)+(x6+x7));
#pragma unroll
  for (int m=1; m<64; m<<=1) sm += __shfl_xor(sm, m, 64);
  float mean = sm * (1.0f/512.0f);
  float d0=x0-mean, d1=x1-mean, d2=x2-mean, d3=x3-mean;
  float d4=x4-mean, d5=x5-mean, d6=x6-mean, d7=x7-mean;
  float s2 = ((d0*d0+d1*d1)+(d2*d2+d3*d3)) + ((d4*d4+d5*d5)+(d6*d6+d7*d7));
#pragma unroll
  for (int m=1; m<64; m<<=1) s2 += __shfl_xor(s2, m, 64);
  float rstd = rsqrtf(s2*(1.0f/512.0f) + 1e-5f);
  const float* gp = g + lane*8; const float* bp = be + lane*8;
  float4 g0 = *(const float4*)gp, g1 = *(const float4*)(gp+4);
  float4 b0 = *(const float4*)bp, b1 = *(const float4*)(bp+4);
  uint4 yo;
  yo.x = bfpack2(d0*rstd*g0.x + b0.x, d1*rstd*g0.y + b0.y);
  yo.y = bfpack2(d2*rstd*g0.z + b0.z, d3*rstd*g0.w + b0.w);
  yo.z = bfpack2(d4*rstd*g1.x + b1.x, d5*rstd*g1.y + b1.y);
  yo.w = bfpack2(d6*rstd*g1.z + b1.z, d7*rstd*g1.w + b1.w);
  *(uint4*)&Y[base] = yo;
}

// ---------------- LayerNorm over 512 reading bf16, 4 rows/block, writes f32
__global__ __launch_bounds__(256) void ln_bf16_kernel(
    const unsigned short* __restrict__ X, const float* __restrict__ g,
    const float* __restrict__ be, float* __restrict__ Y)
{
  int row = blockIdx.x*4 + (threadIdx.x >> 6);
  int lane = threadIdx.x & 63;
  size_t base = (size_t)row*512 + lane*8;
  bf16x8 xv = *(const bf16x8*)&X[base];
  float x0 = bf2f((unsigned short)xv[0]), x1 = bf2f((unsigned short)xv[1]);
  float x2 = bf2f((unsigned short)xv[2]), x3 = bf2f((unsigned short)xv[3]);
  float x4 = bf2f((unsigned short)xv[4]), x5 = bf2f((unsigned short)xv[5]);
  float x6 = bf2f((unsigned short)xv[6]), x7 = bf2f((unsigned short)xv[7]);
  float s = ((x0+x1)+(x2+x3)) + ((x4+x5)+(x6+x7));
#pragma unroll
  for (int m=1; m<64; m<<=1) s += __shfl_xor(s, m, 64);
  float mean = s * (1.0f/512.0f);
  float d0=x0-mean, d1=x1-mean, d2=x2-mean, d3=x3-mean;
  float d4=x4-mean, d5=x5-mean, d6=x6-mean, d7=x7-mean;
  float s2 = ((d0*d0+d1*d1)+(d2*d2+d3*d3)) + ((d4*d4+d5*d5)+(d6*d6+d7*d7));
#pragma unroll
  for (int m=1; m<64; m<<=1) s2 += __shfl_xor(s2, m, 64);
  float rstd = rsqrtf(s2*(1.0f/512.0f) + 1e-5f);
  const float* gp = g + lane*8; const float* bp = be + lane*8;
  float4 g0 = *(const float4*)gp, g1 = *(const float4*)(gp+4);
  float4 b0 = *(const float4*)bp, b1 = *(const float4*)(bp+4);
  float4 y0, y1;
  y0.x = d0*rstd*g0.x + b0.x; y0.y = d1*rstd*g0.y + b0.y;
  y0.z = d2*rstd*g0.z + b0.z; y0.w = d3*rstd*g0.w + b0.w;
  y1.x = d4*rstd*g1.x + b1.x; y1.y = d5*rstd*g1.y + b1.y;
  y1.z = d6*rstd*g1.z + b1.z; y1.w = d7*rstd*g1.w + b1.w;
  float* yp = Y + base;
  *(float4*)yp = y0;
  *(float4*)(yp+4) = y1;
}

extern "C" void kernel_launch(void* const* d_in, const int* in_sizes, int n_in,
                              void* d_out, int out_size, void* d_ws, size_t ws_size,
                              hipStream_t stream) {
  const float* Q    = (const float*)d_in[0];
  const float* K    = (const float*)d_in[1];
  const int*   mask = (const int*)d_in[2];
  const float* temp = (const float*)d_in[3];
  const float* Wq = (const float*)d_in[4];  const float* bq = (const float*)d_in[5];
  const float* Wk = (const float*)d_in[6];  const float* bk = (const float*)d_in[7];
  const float* Wv = (const float*)d_in[8];  const float* bv = (const float*)d_in[9];
  const float* Wo = (const float*)d_in[10]; const float* bo = (const float*)d_in[11];
  const float* g0 = (const float*)d_in[12]; const float* b0 = (const float*)d_in[13];
  const float* g1 = (const float*)d_in[14]; const float* b1 = (const float*)d_in[15];
  float* out = (float*)d_out;
  (void)in_sizes; (void)n_in; (void)out_size; (void)ws_size;

  char* ws = (char*)d_ws;
  unsigned short* qbuf = (unsigned short*)(ws + 0);          // 8.4MB  q proj (bf16)
  unsigned short* kbuf = (unsigned short*)(ws + 8388608);    // 8.4MB  k proj (scaled)
  unsigned short* vtb  = (unsigned short*)(ws + 16777216);   // 8.4MB  v tile-major
  unsigned short* OpA  = (unsigned short*)(ws + 25165824);   // 2x 8.4MB bf16 partials
  unsigned short* WqT  = (unsigned short*)(ws + 41943040);   // 4 x 0.5MB
  unsigned short* WkT  = WqT + 262144;
  unsigned short* WvT  = WqT + 524288;
  unsigned short* WoT  = WqT + 786432;
  float* lbuf = (float*)(ws + 44040192);                     // 512KB per-(row,split,head) sums
  unsigned short* Olnf = (unsigned short*)(ws + 8388608);    // 8.4MB post-LN0 bf16 (alias kbuf)
  unsigned short* O2   = (unsigned short*)(ws + 25165824);   // 8.4MB post-GEMM bf16 (alias OpA)

  wt_kernel<<<dim3(8,8,4), 256, 0, stream>>>(Wq, Wk, Wv, Wo, WqT, WkT, WvT, WoT);
  qkv_kernel<<<dim3(64,4,3), 256, 0, stream>>>(Q, K, WqT, WkT, WvT, bq, bk, bv, temp,
                                               qbuf, kbuf, vtb);
  attn_kernel<<<1024, 256, 0, stream>>>(qbuf, kbuf, vtb, mask, OpA, lbuf);
  combine_ln_kernel<<<2048, 256, 0, stream>>>(OpA, OpA + 4194304, lbuf, qbuf, g0, b0, Olnf);
  gemm_o_kernel<<<dim3(64,4), 256, 0, stream>>>(Olnf, WoT, bo, O2, Olnf);
  ln_bf16_kernel<<<2048, 256, 0, stream>>>(O2, g1, b1, out);
}